// Round 9
// baseline (136.794 us; speedup 1.0000x reference)
//
#include <hip/hip_runtime.h>
#include <math.h>

#define RES_H 256
#define RES_W 256
#define EPSF 1e-9f
#define FLOW_TEMP_REG 1e-3f

#define BAND_SHIFT 4
#define BAND_ROWS 16
#define N_BANDS 16                    // 256/16
#define BAND_PX (BAND_ROWS * RES_W)   // 4096
#define CAP 24576                     // records per bucket (expect ~17.4K)
#define QS 2048.0f                    // Q11 LDS weight fixed point (validated R3-R8)
#define QINV (1.0f / 2048.0f)
#define EV_PER_BLOCK 2048
#define EV_PER_THREAD 8               // 256 threads * 8

#define PAD 32                        // 128-B stride for contended counters

typedef unsigned long long u64;
typedef unsigned int u32;

// max_ts arrives as a 1-element array. Python int -> int32 bits, but be robust.
__device__ __forceinline__ float decode_mt(const int* p) {
    int raw = *p;
    if (raw >= 0 && raw < (1 << 23)) return (float)raw;
    union { int i; float f; } u; u.i = raw; return u.f;
}

// Compact u32 record (band-relative; halves bin-write + accum-read traffic):
//   [0:5)   ryp = iy+1 - band*16   (0..16; ry = ryp-1 in -1..15)
//   [5:14)  ixp = ix+1             (0..256)
//   [14:20) fy * 63  (Q6; (1-fy)+fy == 1 exactly -> mass-preserving)
//   [20:26) fx * 63  (Q6)
//   [26:31) tsw/mt * 31 (Q5)
//   [31]    pol (0=pos)
// Bucket k = dir*16 + band, DENSE two-pass reservation (R7 showed sparse
// private slices lose). Bin pass B recomputes warp math instead of caching
// records in registers (R8 showed the VGPR cost beats the recompute cost).

// ws layout: [0,32KB) counts: 256 buckets * PAD u32 (one line each)
//            [32KB,34KB) partials: 16 bd * PAD floats
//            [34KB,36KB) done: 16 bd * PAD u32; [36KB] done2 root
//            [64KB, +25.2MB) recs: 256 buckets * CAP * 4B

__global__ void __launch_bounds__(256) ew_bin(
    const float4* __restrict__ ev, const float2* __restrict__ flow,
    const int* __restrict__ mt_ptr, u32* __restrict__ recs,
    u32* __restrict__ counts, int N)
{
    __shared__ u32 hist[32], basebuf[32], cursor[32];
    const int b = blockIdx.y;
    const int start = blockIdx.x * EV_PER_BLOCK;
    const int tid = threadIdx.x;
    if (tid < 32) { hist[tid] = 0u; cursor[tid] = 0u; }
    __syncthreads();

    const float mt = decode_mt(mt_ptr);
    const float inv_mt = 1.0f / mt;

    float4 e[EV_PER_THREAD];
    float2 f[EV_PER_THREAD];
    #pragma unroll
    for (int j = 0; j < EV_PER_THREAD; ++j) {
        int i = start + tid + j * 256;
        if (i < N) { e[j] = ev[b * N + i]; f[j] = flow[b * N + i]; }
        else { e[j] = make_float4(0.f, -100.f, -100.f, 1.f); f[j] = make_float2(0.f, 0.f); }
    }

    // pass A: histogram of (dir, band) touches
    #pragma unroll
    for (int j = 0; j < EV_PER_THREAD; ++j) {
        #pragma unroll
        for (int dir = 0; dir < 2; ++dir) {
            float dtt = (dir ? 0.0f : mt) - e[j].x;
            float wy = fminf(fmaxf(e[j].y + dtt * f[j].x, -8.0f), 264.0f);
            float wx = fminf(fmaxf(e[j].z + dtt * f[j].y, -8.0f), 264.0f);
            int iy = (int)floorf(wy), ix = (int)floorf(wx);
            if (iy < -1 || iy > 255 || ix < -1 || ix > 255) continue;
            int t1 = iy >> BAND_SHIFT;         // -1..15 (arith shift handles -1)
            int t2 = (iy + 1) >> BAND_SHIFT;   // 0..16
            if (t1 >= 0) atomicAdd(&hist[dir * 16 + t1], 1u);
            if (t2 <= 15 && t2 != t1) atomicAdd(&hist[dir * 16 + t2], 1u);
        }
    }
    __syncthreads();
    if (tid < 32) basebuf[tid] = atomicAdd(&counts[(b * 32 + tid) * PAD], hist[tid]);
    __syncthreads();

    // pass B: recompute and append compact records (per-target-band ry field)
    #pragma unroll
    for (int j = 0; j < EV_PER_THREAD; ++j) {
        #pragma unroll
        for (int dir = 0; dir < 2; ++dir) {
            float dtt = (dir ? 0.0f : mt) - e[j].x;
            float tswn = (dir ? (mt - e[j].x) : e[j].x) * inv_mt;
            float wy = fminf(fmaxf(e[j].y + dtt * f[j].x, -8.0f), 264.0f);
            float wx = fminf(fmaxf(e[j].z + dtt * f[j].y, -8.0f), 264.0f);
            float tyf = floorf(wy), txf = floorf(wx);
            int iy = (int)tyf, ix = (int)txf;
            if (iy < -1 || iy > 255 || ix < -1 || ix > 255) continue;
            u32 fy6 = __float2uint_rn((wy - tyf) * 63.0f);
            u32 fx6 = __float2uint_rn((wx - txf) * 63.0f);
            u32 tq  = __float2uint_rn(fminf(fmaxf(tswn, 0.0f), 1.0f) * 31.0f);
            u32 base = ((u32)(ix + 1) << 5) | (fy6 << 14) | (fx6 << 20)
                     | (tq << 26) | ((e[j].w > 0.0f ? 0u : 1u) << 31);
            int t1 = iy >> BAND_SHIFT;
            int t2 = (iy + 1) >> BAND_SHIFT;
            #pragma unroll
            for (int s = 0; s < 2; ++s) {
                int t = s ? t2 : t1;
                if (t < 0 || t > 15) continue;
                if (s && t2 == t1) continue;
                int k = dir * 16 + t;
                u32 off = atomicAdd(&cursor[k], 1u);
                u32 slot = basebuf[k] + off;
                if (slot >= CAP) slot = CAP - 1;   // overflow guard (never in practice)
                recs[(size_t)(b * 32 + k) * CAP + slot] =
                    base | (u32)(iy + 1 - (t << BAND_SHIFT));
            }
        }
    }
}

// Fused accumulate + reduce + (globally-last block) finalize. Block (band, bd)
// solely owns its 16x256 tile: LDS u32 per pol plane (lo16 = sum w Q11,
// hi16 = sum w*tsw/mt Q11). Dense bucket read is exact-count and coalesced.
__global__ void __launch_bounds__(1024) ew_accum(
    const u32* __restrict__ recs, const u32* __restrict__ counts,
    float* __restrict__ partials, const float* __restrict__ vec,
    float* __restrict__ out, int B, int P)
{
    __shared__ u32 lds[2 * BAND_PX];   // 32 KB
    __shared__ float wterm[16], wnz[16];
    __shared__ int is_last_s;
    const int band = blockIdx.x, bd = blockIdx.y;
    const int q = bd * 16 + band;      // == (b*2+dir)*16 + band, matches ew_bin
    const int tid = threadIdx.x;
    for (int i = tid; i < 2 * BAND_PX; i += 1024) lds[i] = 0u;
    __syncthreads();

    u32 cnt = counts[q * PAD]; if (cnt > CAP) cnt = CAP;
    const u32* bucket = recs + (size_t)q * CAP;

    for (u32 i = tid; i < cnt; i += 1024) {
        u32 rec = bucket[i];
        int ry = (int)(rec & 31u) - 1;             // -1..15 band-relative
        int ix = (int)((rec >> 5) & 511u) - 1;     // -1..255
        float fy = (float)((rec >> 14) & 63u) * (1.0f / 63.0f);
        float fx = (float)((rec >> 20) & 63u) * (1.0f / 63.0f);
        float tswn = (float)((rec >> 26) & 31u) * (1.0f / 31.0f);
        u32* pl = lds + (rec >> 31) * BAND_PX;
        #pragma unroll
        for (int cc = 0; cc < 4; ++cc) {
            int cy = ry + (cc >> 1), cx = ix + (cc & 1);
            if ((unsigned)cy >= BAND_ROWS || (unsigned)cx >= RES_W) continue;
            float wgt = ((cc >> 1) ? fy : 1.0f - fy) * ((cc & 1) ? fx : 1.0f - fx);
            u32 v = (__float2uint_rn(wgt * tswn * QS) << 16)
                  |  __float2uint_rn(wgt * QS);
            if (v) atomicAdd(&pl[(cy << 8) | cx], v);
        }
    }
    __syncthreads();

    // fused per-pixel reduction: 4096 px, 4/thread via uint4 LDS reads
    const uint4 pp = ((const uint4*)lds)[tid];
    const uint4 nn = ((const uint4*)(lds + BAND_PX))[tid];
    const u32 pu[4] = {pp.x, pp.y, pp.z, pp.w};
    const u32 nu[4] = {nn.x, nn.y, nn.z, nn.w};
    float term = 0.0f, nz = 0.0f;
    #pragma unroll
    for (int j = 0; j < 4; ++j) {
        u32 wp_r = pu[j] & 0xFFFFu, tp_r = pu[j] >> 16;
        u32 wn_r = nu[j] & 0xFFFFu, tn_r = nu[j] >> 16;
        float wp = (float)wp_r * QINV, tp = (float)tp_r * QINV;
        float wn = (float)wn_r * QINV, tn = (float)tn_r * QINV;
        float pts = tp / (wp + EPSF);
        float nts = tn / (wn + EPSF);
        term += pts * pts + nts * nts;
        nz   += ((wp_r | wn_r) != 0u) ? 1.0f : 0.0f;
    }
    #pragma unroll
    for (int off = 32; off > 0; off >>= 1) {
        term += __shfl_down(term, off);
        nz   += __shfl_down(nz, off);
    }
    if ((tid & 63) == 0) { wterm[tid >> 6] = term; wnz[tid >> 6] = nz; }
    __syncthreads();

    u32* done  = (u32*)(partials + 512);    // 16 padded per-bd counters
    u32* done2 = (u32*)(partials + 1024);   // root counter
    if (tid == 0) {
        float t = 0.0f, z = 0.0f;
        #pragma unroll
        for (int wv = 0; wv < 16; ++wv) { t += wterm[wv]; z += wnz[wv]; }
        atomicAdd(&partials[bd * PAD + 0], t);
        atomicAdd(&partials[bd * PAD + 1], z);
        __threadfence();                    // publish before arrival
        int last = 0;
        if (atomicAdd(&done[bd * PAD], 1u) == N_BANDS - 1u) {
            if (atomicAdd(done2, 1u) == 15u) last = 1;
        }
        is_last_s = last;
    }
    __syncthreads();
    if (!is_last_s) return;

    // ---- globally-last block: finalize (loss scaling + smoothness) ----
    __threadfence();   // acquire side of the done protocol
    float v = 0.0f;
    if (tid < 16) {
        float s = __hip_atomic_load(&partials[tid * PAD + 0],
                                    __ATOMIC_RELAXED, __HIP_MEMORY_SCOPE_AGENT);
        float n = __hip_atomic_load(&partials[tid * PAD + 1],
                                    __ATOMIC_RELAXED, __HIP_MEMORY_SCOPE_AGENT);
        v = s / (n + EPSF);   // LOSS_SCALING
    }
    const int per_b = (P - 1) * 8;
    const int tot = B * per_b;
    float sm = 0.0f;
    for (int i = tid; i < tot; i += 1024) {
        int bb = i / per_b;
        int r = i - bb * per_b;
        int pi = r >> 3, j = r & 7;
        float d = vec[(bb * P + pi) * 8 + j] - vec[(bb * P + pi + 1) * 8 + j];
        sm += sqrtf(d * d + EPSF);
    }
    float val = v + sm / (float)per_b * FLOW_TEMP_REG;
    #pragma unroll
    for (int off = 32; off > 0; off >>= 1) val += __shfl_down(val, off);
    if ((tid & 63) == 0) wterm[tid >> 6] = val;
    __syncthreads();
    if (tid == 0) {
        float t = 0.0f;
        #pragma unroll
        for (int wv = 0; wv < 16; ++wv) t += wterm[wv];
        out[0] = t;
    }
}

extern "C" void kernel_launch(void* const* d_in, const int* in_sizes, int n_in,
                              void* d_out, int out_size, void* d_ws, size_t ws_size,
                              hipStream_t stream) {
    const float4* ev   = (const float4*)d_in[0];  // [B,N,4]
    const float2* flow = (const float2*)d_in[1];  // [B,N,2]
    const float*  vec  = (const float*)d_in[3];   // [B,P,8]
    const int*    mtp  = (const int*)d_in[4];     // scalar

    const int B = 8;
    const int N = in_sizes[0] / (B * 4);
    const int P = in_sizes[3] / (B * 8);

    u32*   counts   = (u32*)d_ws;
    float* partials = (float*)((char*)d_ws + 32768);
    u32*   recs     = (u32*)((char*)d_ws + 65536);

    hipMemsetAsync(d_ws, 0, 65536, stream);   // counts + partials + done

    dim3 bgrid((N + EV_PER_BLOCK - 1) / EV_PER_BLOCK, B);   // 128 x 8
    ew_bin<<<bgrid, 256, 0, stream>>>(ev, flow, mtp, recs, counts, N);

    dim3 agrid(N_BANDS, 16);   // 16 x 16 = 256 blocks, 1/CU
    ew_accum<<<agrid, 1024, 0, stream>>>(recs, counts, partials, vec,
                                         (float*)d_out, B, P);
}

// Round 10
// 126.952 us; speedup vs baseline: 1.0775x; 1.0775x over previous
//
#include <hip/hip_runtime.h>
#include <math.h>

#define RES_H 256
#define RES_W 256
#define NPIX 65536
#define EPSF 1e-9f
#define FLOW_TEMP_REG 1e-3f

#define BAND_SHIFT 4
#define BAND_ROWS 16
#define N_BANDS 16                    // 256/16
#define BAND_PX (BAND_ROWS * RES_W)   // 4096
#define CAP 24576                     // records per bucket (expect ~17.4K)
#define QS 2048.0f                    // Q11 weight fixed point (validated R3-R5)
#define QINV (1.0f / 2048.0f)
#define EV_PER_BLOCK 2048
#define EV_PER_THREAD 8               // 256 threads * 8

#define PAD 32                        // 128-B stride for contended counters

typedef unsigned long long u64;
typedef unsigned int u32;

// Best-measured configuration (R6, 127.1 µs). R7 (private slices), R8
// (register-cached records, fused finalize), R9 (compact u32 records) all
// measured neutral-to-negative vs this structure:
//  - dense two-pass buckets beat reservation-free slices (sparsity costs more
//    than the reservation pass);
//  - pass-B recompute beats register caching (occupancy > redundant VALU in
//    the latency-bound scatter);
//  - separate 3 µs finalize launch ~= fused done-counter finalize.

// max_ts arrives as a 1-element array. Python int -> int32 bits, but be robust.
__device__ __forceinline__ float decode_mt(const int* p) {
    int raw = *p;
    if (raw >= 0 && raw < (1 << 23)) return (float)raw;
    union { int i; float f; } u; u.i = raw; return u.f;
}

// Record pack (u64): [0:22) wy*4096 (s10.12) | [22:44) wx*4096 |
//                    [44:57) tsw/mt*4096 (Q13 holds 4096) | [57] pol (0=pos)
// Binning uses quantized iy = wyf>>12 so phase 1/2 band decisions agree exactly.
// Bucket index: (b*2+dir)*N_BANDS + band  (= bd*16 + band in phase 2).

// Phase 1: bin events by (b, dir, 16-row y-band). counts entries padded to one
// cache line each so range-reservation atomics never share a line.
__global__ void __launch_bounds__(256) ew_bin(
    const float4* __restrict__ ev, const float2* __restrict__ flow,
    const int* __restrict__ mt_ptr, u64* __restrict__ recs,
    u32* __restrict__ counts, int N)
{
    __shared__ u32 hist[32], basebuf[32], cursor[32];
    const int b = blockIdx.y;
    const int start = blockIdx.x * EV_PER_BLOCK;
    const int tid = threadIdx.x;
    if (tid < 32) { hist[tid] = 0u; cursor[tid] = 0u; }
    __syncthreads();

    const float mt = decode_mt(mt_ptr);
    const float inv_mt = 1.0f / mt;

    float4 e[EV_PER_THREAD];
    float2 f[EV_PER_THREAD];
    #pragma unroll
    for (int j = 0; j < EV_PER_THREAD; ++j) {
        int i = start + tid + j * 256;
        if (i < N) { e[j] = ev[b * N + i]; f[j] = flow[b * N + i]; }
        else { e[j] = make_float4(0.f, -100.f, -100.f, 1.f); f[j] = make_float2(0.f, 0.f); }
    }

    // pass A: histogram of (dir, band) touches
    #pragma unroll
    for (int j = 0; j < EV_PER_THREAD; ++j) {
        #pragma unroll
        for (int dir = 0; dir < 2; ++dir) {
            float dtt = (dir ? 0.0f : mt) - e[j].x;
            float wy = fminf(fmaxf(e[j].y + dtt * f[j].x, -8.0f), 264.0f);
            float wx = fminf(fmaxf(e[j].z + dtt * f[j].y, -8.0f), 264.0f);
            int wyf = __float2int_rn(wy * 4096.0f);
            int wxf = __float2int_rn(wx * 4096.0f);
            int iy = wyf >> 12, ix = wxf >> 12;
            if (iy < -1 || iy > 255 || ix < -1 || ix > 255) continue;
            int t1 = iy >> BAND_SHIFT;         // -1..15 (arith shift handles -1)
            int t2 = (iy + 1) >> BAND_SHIFT;   // 0..16
            if (t1 >= 0) atomicAdd(&hist[dir * 16 + t1], 1u);
            if (t2 <= 15 && t2 != t1) atomicAdd(&hist[dir * 16 + t2], 1u);
        }
    }
    __syncthreads();
    if (tid < 32) basebuf[tid] = atomicAdd(&counts[(b * 32 + tid) * PAD], hist[tid]);
    __syncthreads();

    // pass B: recompute (from registers) and append packed records
    #pragma unroll
    for (int j = 0; j < EV_PER_THREAD; ++j) {
        #pragma unroll
        for (int dir = 0; dir < 2; ++dir) {
            float dtt = (dir ? 0.0f : mt) - e[j].x;
            float tswn = (dir ? (mt - e[j].x) : e[j].x) * inv_mt;
            float wy = fminf(fmaxf(e[j].y + dtt * f[j].x, -8.0f), 264.0f);
            float wx = fminf(fmaxf(e[j].z + dtt * f[j].y, -8.0f), 264.0f);
            int wyf = __float2int_rn(wy * 4096.0f);
            int wxf = __float2int_rn(wx * 4096.0f);
            int iy = wyf >> 12, ix = wxf >> 12;
            if (iy < -1 || iy > 255 || ix < -1 || ix > 255) continue;
            u32 tq = __float2uint_rn(fminf(fmaxf(tswn, 0.0f), 1.0f) * 4096.0f);
            u64 rec = (u64)((u32)wyf & 0x3FFFFFu)
                    | ((u64)((u32)wxf & 0x3FFFFFu) << 22)
                    | ((u64)tq << 44)
                    | ((u64)(e[j].w > 0.0f ? 0u : 1u) << 57);
            int t1 = iy >> BAND_SHIFT;
            int t2 = (iy + 1) >> BAND_SHIFT;
            #pragma unroll
            for (int s = 0; s < 2; ++s) {
                int t = s ? t2 : t1;
                if (t < 0 || t > 15) continue;
                if (s && t2 == t1) continue;
                int k = dir * 16 + t;
                u32 off = atomicAdd(&cursor[k], 1u);
                u32 slot = basebuf[k] + off;
                if (slot >= CAP) slot = CAP - 1;   // overflow guard (never in practice)
                recs[(size_t)(b * 32 + k) * CAP + slot] = rec;
            }
        }
    }
}

// Phase 2 (fused accumulate + reduce): block = (band, bd) is the SOLE owner of
// its 16x256 tile. Reads only its bucket (coalesced), accumulates into LDS
// (u32 per pol plane: lo16 = sum w Q11, hi16 = sum w*tsw/mt Q11), then computes
// the per-pixel loss terms directly from LDS — no accum array, no reduce pass.
__global__ void __launch_bounds__(1024) ew_accum(
    const u64* __restrict__ recs, const u32* __restrict__ counts,
    float* __restrict__ partials)
{
    __shared__ u32 lds[2 * BAND_PX];   // 32 KB
    __shared__ float wterm[16], wnz[16];
    const int band = blockIdx.x, bd = blockIdx.y;
    const int q = bd * 16 + band;      // == (b*2+dir)*16 + band, matches ew_bin
    const int row0 = band << BAND_SHIFT;
    const int tid = threadIdx.x;
    for (int i = tid; i < 2 * BAND_PX; i += 1024) lds[i] = 0u;
    __syncthreads();

    u32 cnt = counts[q * PAD]; if (cnt > CAP) cnt = CAP;
    const u64* bucket = recs + (size_t)q * CAP;

    for (u32 i = tid; i < cnt; i += 1024) {
        u64 rec = bucket[i];
        int wyf = ((int)(((u32)rec & 0x3FFFFFu) << 10)) >> 10;
        int wxf = ((int)(((u32)(rec >> 22) & 0x3FFFFFu) << 10)) >> 10;
        float tswn = (float)((u32)(rec >> 44) & 0x1FFFu) * (1.0f / 4096.0f);
        u32 pol = (u32)(rec >> 57) & 1u;
        int ry = (wyf >> 12) - row0;   // -1..16 for this band
        int ix = wxf >> 12;
        float fy = (float)(wyf & 0xFFF) * (1.0f / 4096.0f);
        float fx = (float)(wxf & 0xFFF) * (1.0f / 4096.0f);
        u32* pl = lds + pol * BAND_PX;
        #pragma unroll
        for (int cc = 0; cc < 4; ++cc) {
            int cy = ry + (cc >> 1), cx = ix + (cc & 1);
            if ((unsigned)cy >= BAND_ROWS || (unsigned)cx >= RES_W) continue;
            float wgt = ((cc >> 1) ? fy : 1.0f - fy) * ((cc & 1) ? fx : 1.0f - fx);
            u32 v = (__float2uint_rn(wgt * tswn * QS) << 16)
                  |  __float2uint_rn(wgt * QS);
            if (v) atomicAdd(&pl[(cy << 8) | cx], v);
        }
    }
    __syncthreads();

    // fused per-pixel reduction: 4096 px, 4 per thread via uint4 LDS reads
    const uint4 pp = ((const uint4*)lds)[tid];
    const uint4 nn = ((const uint4*)(lds + BAND_PX))[tid];
    const u32 pu[4] = {pp.x, pp.y, pp.z, pp.w};
    const u32 nu[4] = {nn.x, nn.y, nn.z, nn.w};
    float term = 0.0f, nz = 0.0f;
    #pragma unroll
    for (int j = 0; j < 4; ++j) {
        u32 wp_r = pu[j] & 0xFFFFu, tp_r = pu[j] >> 16;
        u32 wn_r = nu[j] & 0xFFFFu, tn_r = nu[j] >> 16;
        float wp = (float)wp_r * QINV, tp = (float)tp_r * QINV;
        float wn = (float)wn_r * QINV, tn = (float)tn_r * QINV;
        float pts = tp / (wp + EPSF);
        float nts = tn / (wn + EPSF);
        term += pts * pts + nts * nts;
        nz   += ((wp_r | wn_r) != 0u) ? 1.0f : 0.0f;
    }
    #pragma unroll
    for (int off = 32; off > 0; off >>= 1) {
        term += __shfl_down(term, off);
        nz   += __shfl_down(nz, off);
    }
    if ((tid & 63) == 0) { wterm[tid >> 6] = term; wnz[tid >> 6] = nz; }
    __syncthreads();
    if (tid == 0) {
        float t = 0.0f, z = 0.0f;
        #pragma unroll
        for (int wv = 0; wv < 16; ++wv) { t += wterm[wv]; z += wnz[wv]; }
        atomicAdd(&partials[bd * PAD + 0], t);
        atomicAdd(&partials[bd * PAD + 1], z);
    }
}

// Single block: per-(b,dir) loss scaling + Charbonnier smoothness, write loss.
__global__ void __launch_bounds__(256) ew_finalize(
    const float* __restrict__ partials, const float* __restrict__ vec,
    float* __restrict__ out, int B, int P, int n_bd)
{
    int tid = threadIdx.x;
    float v = 0.0f;
    if (tid < n_bd) {
        float s = partials[tid * PAD + 0];
        float n = partials[tid * PAD + 1];
        v = s / (n + EPSF);   // LOSS_SCALING
    }
    int per_b = (P - 1) * 8;
    int total = B * per_b;
    float sm = 0.0f;
    for (int i = tid; i < total; i += blockDim.x) {
        int b = i / per_b;
        int r = i - b * per_b;
        int pi = r >> 3, j = r & 7;
        float d = vec[(b * P + pi) * 8 + j] - vec[(b * P + pi + 1) * 8 + j];
        sm += sqrtf(d * d + EPSF);
    }
    sm = sm / (float)per_b * FLOW_TEMP_REG;

    __shared__ float sdata[256];
    sdata[tid] = v + sm;
    __syncthreads();
    for (int s = 128; s > 0; s >>= 1) {
        if (tid < s) sdata[tid] += sdata[tid + s];
        __syncthreads();
    }
    if (tid == 0) out[0] = sdata[0];
}

extern "C" void kernel_launch(void* const* d_in, const int* in_sizes, int n_in,
                              void* d_out, int out_size, void* d_ws, size_t ws_size,
                              hipStream_t stream) {
    const float4* ev   = (const float4*)d_in[0];  // [B,N,4]
    const float2* flow = (const float2*)d_in[1];  // [B,N,2]
    const float*  vec  = (const float*)d_in[3];   // [B,P,8]
    const int*    mtp  = (const int*)d_in[4];     // scalar

    const int B = 8;
    const int N = in_sizes[0] / (B * 4);
    const int P = in_sizes[3] / (B * 8);

    // ws layout: [0,32KB) counts: 256 buckets * PAD u32 (one line each)
    //            [32KB,34KB) partials: 16 bd * PAD floats
    //            [64KB, +50.3MB) recs: 256 buckets * CAP * 8B
    u32*   counts   = (u32*)d_ws;
    float* partials = (float*)((char*)d_ws + 32768);
    u64*   recs     = (u64*)((char*)d_ws + 65536);

    hipMemsetAsync(d_ws, 0, 65536, stream);   // counts + partials

    dim3 bgrid((N + EV_PER_BLOCK - 1) / EV_PER_BLOCK, B);   // 128 x 8
    ew_bin<<<bgrid, 256, 0, stream>>>(ev, flow, mtp, recs, counts, N);

    dim3 agrid(N_BANDS, 16);                                 // 16 x 16 = 256
    ew_accum<<<agrid, 1024, 0, stream>>>(recs, counts, partials);

    ew_finalize<<<1, 256, 0, stream>>>(partials, vec, (float*)d_out, B, P, 16);
}